// Round 4
// baseline (968.692 us; speedup 1.0000x reference)
//
#include <hip/hip_runtime.h>

#define DIN 150528
#define DD 512
#define NC 100
#define NM 64
#define NFEAT 256
#define EPSF 1e-6f
#define KSTEPS (DIN / 32) /* 4704 */

typedef float f32x4 __attribute__((ext_vector_type(4)));
typedef __bf16 bf16x8 __attribute__((ext_vector_type(8)));
typedef unsigned short u16x8 __attribute__((ext_vector_type(8)));

static __device__ __forceinline__ unsigned short f2bf(float x) {
  unsigned int u = __builtin_bit_cast(unsigned int, x);
  u += 0x7FFFu + ((u >> 16) & 1u);  // RNE
  return (unsigned short)(u >> 16);
}
static __device__ __forceinline__ float bf2f(unsigned short h) {
  return __builtin_bit_cast(float, ((unsigned int)h) << 16);
}

// ---------------------------------------------------------------------------
// Kernel 1: f_part[s] = image @ W_enc (k-slice s), split-K over 256 blocks.
// v3: back to v1 geometry (256 thr = 4 waves, wave owns N-range [w*128,+128),
// acc[4][8], launch_bounds(256,1) -> 512-reg budget) PLUS explicit two-deep
// register double-buffer: issue ALL 72 loads for step s+1 into the alternate
// statically-named buffer set, then convert+MFMA step s. Barrier-free kernel
// -> no vmcnt(0) drain points; one full k-step (~24 KB/wave, ~96 KB/CU) stays
// in flight through the VALU phase. [Round-2 post-mortem: the 512-thr N=64
// variant got VGPR=64 -> compiler serialized load/convert batches -> 729 GB/s
// latency-bound. Outstanding-bytes/wave, not occupancy, is the constraint.]
// MFMA 16x16x32 bf16: A[m=lane&15][k=quad*8+j], B[k=quad*8+j][n=lane&15],
// C: col=lane&15, row=quad*4+reg (learn_hip m89-verified layouts).
// ---------------------------------------------------------------------------
#define GLOAD(ALO, AHI, WR, S)                                                \
  {                                                                           \
    const int k0_ = (S) * 32;                                                 \
    _Pragma("unroll") for (int mt = 0; mt < 4; ++mt) {                        \
      const float* ap =                                                       \
          image + (size_t)(mt * 16 + r16) * DIN + (k0_ + q * 8);              \
      ALO[mt] = *(const f32x4*)ap;                                            \
      AHI[mt] = *(const f32x4*)(ap + 4);                                      \
    }                                                                         \
    _Pragma("unroll") for (int nt = 0; nt < 8; ++nt) {                        \
      const float* wp =                                                       \
          W + (size_t)(k0_ + q * 8) * DD + (nb + nt * 16 + r16);              \
      _Pragma("unroll") for (int j = 0; j < 8; ++j) WR[nt][j] =               \
          wp[(size_t)j * DD];                                                 \
    }                                                                         \
  }

#define GCOMP(ALO, AHI, WR)                                                   \
  {                                                                           \
    bf16x8 av[4];                                                             \
    _Pragma("unroll") for (int mt = 0; mt < 4; ++mt) {                        \
      u16x8 u;                                                                \
      u[0] = f2bf(ALO[mt][0]); u[1] = f2bf(ALO[mt][1]);                       \
      u[2] = f2bf(ALO[mt][2]); u[3] = f2bf(ALO[mt][3]);                       \
      u[4] = f2bf(AHI[mt][0]); u[5] = f2bf(AHI[mt][1]);                       \
      u[6] = f2bf(AHI[mt][2]); u[7] = f2bf(AHI[mt][3]);                       \
      av[mt] = __builtin_bit_cast(bf16x8, u);                                 \
    }                                                                         \
    bf16x8 bv[8];                                                             \
    _Pragma("unroll") for (int nt = 0; nt < 8; ++nt) {                        \
      u16x8 u;                                                                \
      _Pragma("unroll") for (int j = 0; j < 8; ++j) u[j] = f2bf(WR[nt][j]);   \
      bv[nt] = __builtin_bit_cast(bf16x8, u);                                 \
    }                                                                         \
    _Pragma("unroll") for (int mt = 0; mt < 4; ++mt)                          \
        _Pragma("unroll") for (int nt = 0; nt < 8; ++nt) acc[mt][nt] =        \
            __builtin_amdgcn_mfma_f32_16x16x32_bf16(av[mt], bv[nt],           \
                                                    acc[mt][nt], 0, 0, 0);    \
  }

__global__ __launch_bounds__(256, 1) void gemm_f(
    const float* __restrict__ image, const float* __restrict__ W,
    float* __restrict__ f_part) {
  const int tid = threadIdx.x;
  const int wv = tid >> 6;
  const int lane = tid & 63;
  const int q = lane >> 4;
  const int r16 = lane & 15;
  const int nb = wv * 128;

  f32x4 acc[4][8];
#pragma unroll
  for (int mt = 0; mt < 4; ++mt)
#pragma unroll
    for (int nt = 0; nt < 8; ++nt)
#pragma unroll
      for (int r = 0; r < 4; ++r) acc[mt][nt][r] = 0.0f;

  const int b = blockIdx.x;                 // grid must be 256
  const int s0 = (b * KSTEPS) >> 8;
  const int s1 = ((b + 1) * KSTEPS) >> 8;

  f32x4 alo0[4], ahi0[4], alo1[4], ahi1[4];
  float wr0[8][8], wr1[8][8];

  int s = s0;
  GLOAD(alo0, ahi0, wr0, s);
  while (true) {
    if (s + 1 < s1) GLOAD(alo1, ahi1, wr1, s + 1);
    GCOMP(alo0, ahi0, wr0);
    ++s;
    if (s >= s1) break;
    if (s + 1 < s1) GLOAD(alo0, ahi0, wr0, s + 1);
    GCOMP(alo1, ahi1, wr1);
    ++s;
    if (s >= s1) break;
  }

  float* outp = f_part + (size_t)b * (NM * DD);
#pragma unroll
  for (int mt = 0; mt < 4; ++mt)
#pragma unroll
    for (int nt = 0; nt < 8; ++nt) {
      const int n = nb + nt * 16 + r16;
#pragma unroll
      for (int r = 0; r < 4; ++r) {
        const int m = mt * 16 + q * 4 + r;
        outp[m * DD + n] = acc[mt][nt][r];
      }
    }
}

// ---------------------------------------------------------------------------
// Kernel 1b: f[m][n] = sum_s f_part[s][m][n]. Grid 256 = (64 m) x (4 n-chunks),
// 128 threads = one column each, fully coalesced (512B per s per wave-half).
// ---------------------------------------------------------------------------
__global__ __launch_bounds__(128) void reduce_f(
    const float* __restrict__ f_part, float* __restrict__ f) {
  const int m = blockIdx.x >> 2;
  const int n = (blockIdx.x & 3) * 128 + threadIdx.x;
  const float* p = f_part + (size_t)m * DD + n;
  float s = 0.0f;
#pragma unroll 32
  for (int sdx = 0; sdx < 256; ++sdx) s += p[(size_t)sdx * (NM * DD)];
  f[m * DD + n] = s;
}

// ---------------------------------------------------------------------------
// Kernel 2: row-normalize f -> fn. grid 64 x 64 threads.
// ---------------------------------------------------------------------------
__global__ void norm_f(const float* __restrict__ f, float* __restrict__ fn) {
  const int b = blockIdx.x;
  const int t = threadIdx.x;  // 64
  float s = 0.0f;
#pragma unroll
  for (int i = 0; i < 8; ++i) {
    float v = f[b * DD + t + i * 64];
    s += v * v;
  }
#pragma unroll
  for (int o = 32; o; o >>= 1) s += __shfl_xor(s, o);
  const float inv = 1.0f / sqrtf(s);
#pragma unroll
  for (int i = 0; i < 8; ++i)
    fn[b * DD + t + i * 64] = f[b * DD + t + i * 64] * inv;
}

// ---------------------------------------------------------------------------
// Kernel 3: per class c: gather keys_sel (64x256) & text_sel (100x256),
// L = keys_sel @ text_sel^T via bf16 MFMA (M=64,N=112pad,K=256, K in 2 halves
// to fit 64KB LDS), softmax over j2, p_cc -> w[m], then kw[c][j]=sum_m w*ksel.
// ---------------------------------------------------------------------------
__global__ __launch_bounds__(256) void wk_kernel(
    const float* __restrict__ text, const float* __restrict__ keys,
    const int* __restrict__ indices, const float* __restrict__ pgamma,
    float* __restrict__ kw_buf) {
  const int c = blockIdx.x;
  const int t = threadIdx.x;
  const int wv = t >> 6, lane = t & 63;
  const int q = lane >> 4, r16 = lane & 15;

  __shared__ __align__(16) unsigned short A_lds[64 * 264];   // 33792 B, full K
  __shared__ __align__(16) unsigned short B_lds[112 * 136];  // 30464 B, K-half
  __shared__ __align__(16) int idx_s[256];                   // 1024 B

  idx_s[t] = indices[c * 256 + t];
  __syncthreads();

  // Gather A (keys_sel) full K, bf16. thread t = column j.
  {
    const int j = t;
    const float* kp = keys + (size_t)c * 64 * 512 + idx_s[j];
#pragma unroll 8
    for (int m = 0; m < 64; ++m) A_lds[m * 264 + j] = f2bf(kp[(size_t)m * 512]);
  }

  f32x4 acc[7];
#pragma unroll
  for (int nt = 0; nt < 7; ++nt)
#pragma unroll
    for (int r = 0; r < 4; ++r) acc[nt][r] = 0.0f;
  const int mt = wv;

  for (int kh = 0; kh < 2; ++kh) {
    __syncthreads();  // previous B reads (or A writes) complete
    {
      const int kk = t & 127;
      const float* tp = text + idx_s[kh * 128 + kk];
      for (int n = (t >> 7); n < 112; n += 2)
        B_lds[n * 136 + kk] =
            (n < NC) ? f2bf(tp[(size_t)n * 512]) : (unsigned short)0;
    }
    __syncthreads();
#pragma unroll
    for (int ks = 0; ks < 4; ++ks) {
      bf16x8 afr = *(const bf16x8*)(A_lds + (mt * 16 + r16) * 264 + kh * 128 +
                                    ks * 32 + q * 8);
#pragma unroll
      for (int nt = 0; nt < 7; ++nt) {
        bf16x8 bfr =
            *(const bf16x8*)(B_lds + (nt * 16 + r16) * 136 + ks * 32 + q * 8);
        acc[nt] = __builtin_amdgcn_mfma_f32_16x16x32_bf16(afr, bfr, acc[nt],
                                                          0, 0, 0);
      }
    }
  }
  __syncthreads();

  // C (64x113 fp32) overlays B_lds (28928 <= 30464 B).
  float* C_lds = reinterpret_cast<float*>(B_lds);
#pragma unroll
  for (int nt = 0; nt < 7; ++nt) {
    const int j2 = nt * 16 + r16;
#pragma unroll
    for (int r = 0; r < 4; ++r) {
      const int m = mt * 16 + q * 4 + r;
      C_lds[m * 113 + j2] = acc[nt][r];
    }
  }
  __syncthreads();

  float* w_lds = reinterpret_cast<float*>(idx_s);  // idx no longer needed
  if (t < 64) {
    const int m = t;
    float mx = -1e30f;
    for (int j2 = 0; j2 < NC; ++j2) mx = fmaxf(mx, C_lds[m * 113 + j2]);
    float sum = 0.0f;
    for (int j2 = 0; j2 < NC; ++j2) sum += expf(C_lds[m * 113 + j2] - mx);
    const float p = expf(C_lds[m * 113 + c] - mx) / sum;
    const float KL = log2f((1.0f + EPSF) / (p + EPSF));
    w_lds[m] = expf(KL * (*pgamma));
  }
  __syncthreads();
  {
    const int j = t;
    float kwv = 0.0f;
#pragma unroll 8
    for (int m = 0; m < 64; ++m) kwv += w_lds[m] * bf2f(A_lds[m * 264 + j]);
    kw_buf[c * 256 + j] = kwv;
  }
}

// ---------------------------------------------------------------------------
// Kernel 4: out[b][c] = alpha*exp(beta*cache-beta) + exp(ls)*dot(fn_b,text_c)
// cache = (1/64) * sum_j fn[b][idx[c][j]] * kw[c][j].  grid 100 x 256.
// Barrier-free: wave w handles b = w, w+4, ... — shuffle reductions only.
// ---------------------------------------------------------------------------
__global__ __launch_bounds__(256) void final_kernel(
    const float* __restrict__ fn, const float* __restrict__ text,
    const int* __restrict__ indices, const float* __restrict__ kw_buf,
    const float* __restrict__ pls, const float* __restrict__ palpha,
    const float* __restrict__ pbeta, float* __restrict__ out) {
  const int c = blockIdx.x;
  const int wv = threadIdx.x >> 6, lane = threadIdx.x & 63;

  int idx4[4];
  float kw4[4];
#pragma unroll
  for (int i = 0; i < 4; ++i) {
    idx4[i] = indices[c * 256 + i * 64 + lane];
    kw4[i] = kw_buf[c * 256 + i * 64 + lane];
  }
  float tc[8];
#pragma unroll
  for (int i = 0; i < 8; ++i) tc[i] = text[c * 512 + i * 64 + lane];
  const float ls = expf(*pls);
  const float alpha = *palpha, beta = *pbeta;

  for (int b = wv; b < 64; b += 4) {
    const float* fr = fn + b * DD;
    float cp = 0.0f, lp = 0.0f;
#pragma unroll
    for (int i = 0; i < 4; ++i) cp += fr[idx4[i]] * kw4[i];
#pragma unroll
    for (int i = 0; i < 8; ++i) lp += fr[i * 64 + lane] * tc[i];
#pragma unroll
    for (int o = 32; o; o >>= 1) {
      cp += __shfl_xor(cp, o);
      lp += __shfl_xor(lp, o);
    }
    if (lane == 0)
      out[b * NC + c] =
          alpha * expf(beta * (cp * (1.0f / 64.0f)) - beta) + ls * lp;
  }
}

// ---------------------------------------------------------------------------
extern "C" void kernel_launch(void* const* d_in, const int* in_sizes, int n_in,
                              void* d_out, int out_size, void* d_ws,
                              size_t ws_size, hipStream_t stream) {
  const float* image = (const float*)d_in[0];
  const float* W = (const float*)d_in[1];
  const float* text = (const float*)d_in[2];
  const float* keys = (const float*)d_in[3];
  const float* pls = (const float*)d_in[4];
  const int* idx = (const int*)d_in[5];
  const float* palpha = (const float*)d_in[6];
  const float* pbeta = (const float*)d_in[7];
  const float* pgamma = (const float*)d_in[8];
  float* out = (float*)d_out;

  char* ws = (char*)d_ws;
  float* f_part = (float*)(ws);                  // 256*64*512*4 = 33554432 B
  float* f_buf = (float*)(ws + 33554432);        // 64*512*4     = 131072 B
  float* fn = (float*)(ws + 33554432 + 131072);  // 64*512*4     = 131072 B
  float* kw = (float*)(ws + 33554432 + 262144);  // 100*256*4    = 102400 B

  gemm_f<<<256, 256, 0, stream>>>(image, W, f_part);
  reduce_f<<<256, 128, 0, stream>>>(f_part, f_buf);
  norm_f<<<64, 64, 0, stream>>>(f_buf, fn);
  wk_kernel<<<NC, 256, 0, stream>>>(text, keys, idx, pgamma, kw);
  final_kernel<<<NC, 256, 0, stream>>>(fn, text, idx, kw, pls, palpha, pbeta,
                                       out);
}

// Round 5
// 518.188 us; speedup vs baseline: 1.8694x; 1.8694x over previous
//
#include <hip/hip_runtime.h>

#define DIN 150528
#define DD 512
#define NC 100
#define NM 64
#define NFEAT 256
#define EPSF 1e-6f
#define KSTEPS (DIN / 32) /* 4704 */

typedef float f32x4 __attribute__((ext_vector_type(4)));
typedef __bf16 bf16x8 __attribute__((ext_vector_type(8)));
typedef unsigned short u16x8 __attribute__((ext_vector_type(8)));

static __device__ __forceinline__ unsigned short f2bf(float x) {
  unsigned int u = __builtin_bit_cast(unsigned int, x);
  u += 0x7FFFu + ((u >> 16) & 1u);  // RNE
  return (unsigned short)(u >> 16);
}
static __device__ __forceinline__ float bf2f(unsigned short h) {
  return __builtin_bit_cast(float, ((unsigned int)h) << 16);
}

// ---------------------------------------------------------------------------
// Kernel 1: f_part[s] = image @ W_enc (k-slice s), split-K over 256 blocks.
// v4: W k-step tile (32x512 fp32 = 64 KB, CONTIGUOUS in memory) staged into
// LDS via __builtin_amdgcn_global_load_lds (width 16) — zero destination
// VGPRs, double-buffered (2x64 KB LDS), ONE barrier per step placed AFTER
// compute so the compiler's vmcnt(0)-at-barrier drain overlaps the next
// tile's 64 KB stream with this step's convert+MFMA.
// [Round-4 post-mortem: register double-buffer needs >256 arch VGPRs ->
//  spilled to scratch: WRITE_SIZE 478 MB, 1.5 TB/s, 580 us. Arch-VGPR cap
//  is 256; one k-step of operands (~104 regs) is the register-file max.]
// A (image rows) direct-to-register from global, L1-hot (4x wave redundancy
// is cache-absorbed; unique 8 KB/step). A-convert waits vmcnt(16) — only the
// A loads — because A-loads are issued BEFORE the 16 stage instructions.
// MFMA 16x16x32 bf16: A[m=lane&15][k=quad*8+j], B[k=quad*8+j][n=lane&15],
// C: col=lane&15, row=quad*4+reg (learn_hip m89-verified layouts).
// ---------------------------------------------------------------------------
__global__ __launch_bounds__(256, 1) void gemm_f(
    const float* __restrict__ image, const float* __restrict__ W,
    float* __restrict__ f_part) {
  const int tid = threadIdx.x;
  const int wv = tid >> 6;
  const int lane = tid & 63;
  const int q = lane >> 4;
  const int r16 = lane & 15;
  const int nb = wv * 128;

  __shared__ __align__(16) float Wlds[2][32 * DD];  // 131072 B

  f32x4 acc[4][8];
#pragma unroll
  for (int mt = 0; mt < 4; ++mt)
#pragma unroll
    for (int nt = 0; nt < 8; ++nt)
#pragma unroll
      for (int r = 0; r < 4; ++r) acc[mt][nt][r] = 0.0f;

  const int b = blockIdx.x;                 // grid must be 256
  const int s0 = (b * KSTEPS) >> 8;
  const int s1 = ((b + 1) * KSTEPS) >> 8;

  // Stage k-step s's W tile (64 KB contiguous) into Wlds[buf].
  // 64 wave-insts x 1024 B; this wave's 16 insts cover [wv*16K, wv*16K+16K).
  auto stage = [&](int s, int buf) {
    const char* gsrc = (const char*)(W + (size_t)s * 32 * DD);
    char* lbase = (char*)(&Wlds[buf][0]);
    const int woff = wv << 14;  // wv * 16384
#pragma unroll
    for (int i = 0; i < 16; ++i) {
      const int off = woff + (i << 10);
      __builtin_amdgcn_global_load_lds(
          (const __attribute__((address_space(1))) void*)(gsrc + off +
                                                          (lane << 4)),
          (__attribute__((address_space(3))) void*)(lbase + off), 16, 0, 0);
    }
  };

  stage(s0, 0);
  __syncthreads();  // buf0 resident (vmcnt(0) drain — prologue only)

  int cur = 0;
  for (int s = s0; s < s1; ++s) {
    // 1. A-loads for this step (issued FIRST -> wait = vmcnt(16), A only)
    const int k0 = s * 32;
    f32x4 alo[4], ahi[4];
#pragma unroll
    for (int mt = 0; mt < 4; ++mt) {
      const float* ap = image + (size_t)(mt * 16 + r16) * DIN + (k0 + q * 8);
      alo[mt] = *(const f32x4*)ap;
      ahi[mt] = *(const f32x4*)(ap + 4);
    }
    // 2. prefetch next W tile into the other buffer (stays in flight
    //    through compute; drained only at the end-of-step barrier)
    if (s + 1 < s1) stage(s + 1, cur ^ 1);

    // 3. compute step s from Wlds[cur]
    bf16x8 av[4];
#pragma unroll
    for (int mt = 0; mt < 4; ++mt) {
      u16x8 u;
      u[0] = f2bf(alo[mt][0]); u[1] = f2bf(alo[mt][1]);
      u[2] = f2bf(alo[mt][2]); u[3] = f2bf(alo[mt][3]);
      u[4] = f2bf(ahi[mt][0]); u[5] = f2bf(ahi[mt][1]);
      u[6] = f2bf(ahi[mt][2]); u[7] = f2bf(ahi[mt][3]);
      av[mt] = __builtin_bit_cast(bf16x8, u);
    }
    const float* wb = &Wlds[cur][0];
#pragma unroll
    for (int nt = 0; nt < 8; ++nt) {
      u16x8 u;
#pragma unroll
      for (int j = 0; j < 8; ++j)
        u[j] = f2bf(wb[(q * 8 + j) * DD + nb + nt * 16 + r16]);
      const bf16x8 bvv = __builtin_bit_cast(bf16x8, u);
#pragma unroll
      for (int mt = 0; mt < 4; ++mt)
        acc[mt][nt] = __builtin_amdgcn_mfma_f32_16x16x32_bf16(
            av[mt], bvv, acc[mt][nt], 0, 0, 0);
    }

    // 4. barrier AFTER compute: drains the s+1 prefetch (which streamed
    //    during step 3) and releases buf cur for re-staging at s+2.
    __syncthreads();
    cur ^= 1;
  }

  float* outp = f_part + (size_t)b * (NM * DD);
#pragma unroll
  for (int mt = 0; mt < 4; ++mt)
#pragma unroll
    for (int nt = 0; nt < 8; ++nt) {
      const int n = nb + nt * 16 + r16;
#pragma unroll
      for (int r = 0; r < 4; ++r) {
        const int m = mt * 16 + q * 4 + r;
        outp[m * DD + n] = acc[mt][nt][r];
      }
    }
}

// ---------------------------------------------------------------------------
// Kernel 1b: f[m][n] = sum_s f_part[s][m][n]. Grid 256 = (64 m) x (4 n-chunks),
// 128 threads = one column each, fully coalesced (512B per s per wave-half).
// ---------------------------------------------------------------------------
__global__ __launch_bounds__(128) void reduce_f(
    const float* __restrict__ f_part, float* __restrict__ f) {
  const int m = blockIdx.x >> 2;
  const int n = (blockIdx.x & 3) * 128 + threadIdx.x;
  const float* p = f_part + (size_t)m * DD + n;
  float s = 0.0f;
#pragma unroll 32
  for (int sdx = 0; sdx < 256; ++sdx) s += p[(size_t)sdx * (NM * DD)];
  f[m * DD + n] = s;
}

// ---------------------------------------------------------------------------
// Kernel 2: row-normalize f -> fn. grid 64 x 64 threads.
// ---------------------------------------------------------------------------
__global__ void norm_f(const float* __restrict__ f, float* __restrict__ fn) {
  const int b = blockIdx.x;
  const int t = threadIdx.x;  // 64
  float s = 0.0f;
#pragma unroll
  for (int i = 0; i < 8; ++i) {
    float v = f[b * DD + t + i * 64];
    s += v * v;
  }
#pragma unroll
  for (int o = 32; o; o >>= 1) s += __shfl_xor(s, o);
  const float inv = 1.0f / sqrtf(s);
#pragma unroll
  for (int i = 0; i < 8; ++i)
    fn[b * DD + t + i * 64] = f[b * DD + t + i * 64] * inv;
}

// ---------------------------------------------------------------------------
// Kernel 3: per class c: gather keys_sel (64x256) & text_sel (100x256),
// L = keys_sel @ text_sel^T via bf16 MFMA (M=64,N=112pad,K=256, K in 2 halves
// to fit 64KB LDS), softmax over j2, p_cc -> w[m], then kw[c][j]=sum_m w*ksel.
// ---------------------------------------------------------------------------
__global__ __launch_bounds__(256) void wk_kernel(
    const float* __restrict__ text, const float* __restrict__ keys,
    const int* __restrict__ indices, const float* __restrict__ pgamma,
    float* __restrict__ kw_buf) {
  const int c = blockIdx.x;
  const int t = threadIdx.x;
  const int wv = t >> 6, lane = t & 63;
  const int q = lane >> 4, r16 = lane & 15;

  __shared__ __align__(16) unsigned short A_lds[64 * 264];   // 33792 B, full K
  __shared__ __align__(16) unsigned short B_lds[112 * 136];  // 30464 B, K-half
  __shared__ __align__(16) int idx_s[256];                   // 1024 B

  idx_s[t] = indices[c * 256 + t];
  __syncthreads();

  // Gather A (keys_sel) full K, bf16. thread t = column j.
  {
    const int j = t;
    const float* kp = keys + (size_t)c * 64 * 512 + idx_s[j];
#pragma unroll 8
    for (int m = 0; m < 64; ++m) A_lds[m * 264 + j] = f2bf(kp[(size_t)m * 512]);
  }

  f32x4 acc[7];
#pragma unroll
  for (int nt = 0; nt < 7; ++nt)
#pragma unroll
    for (int r = 0; r < 4; ++r) acc[nt][r] = 0.0f;
  const int mt = wv;

  for (int kh = 0; kh < 2; ++kh) {
    __syncthreads();  // previous B reads (or A writes) complete
    {
      const int kk = t & 127;
      const float* tp = text + idx_s[kh * 128 + kk];
      for (int n = (t >> 7); n < 112; n += 2)
        B_lds[n * 136 + kk] =
            (n < NC) ? f2bf(tp[(size_t)n * 512]) : (unsigned short)0;
    }
    __syncthreads();
#pragma unroll
    for (int ks = 0; ks < 4; ++ks) {
      bf16x8 afr = *(const bf16x8*)(A_lds + (mt * 16 + r16) * 264 + kh * 128 +
                                    ks * 32 + q * 8);
#pragma unroll
      for (int nt = 0; nt < 7; ++nt) {
        bf16x8 bfr =
            *(const bf16x8*)(B_lds + (nt * 16 + r16) * 136 + ks * 32 + q * 8);
        acc[nt] = __builtin_amdgcn_mfma_f32_16x16x32_bf16(afr, bfr, acc[nt],
                                                          0, 0, 0);
      }
    }
  }
  __syncthreads();

  // C (64x113 fp32) overlays B_lds (28928 <= 30464 B).
  float* C_lds = reinterpret_cast<float*>(B_lds);
#pragma unroll
  for (int nt = 0; nt < 7; ++nt) {
    const int j2 = nt * 16 + r16;
#pragma unroll
    for (int r = 0; r < 4; ++r) {
      const int m = mt * 16 + q * 4 + r;
      C_lds[m * 113 + j2] = acc[nt][r];
    }
  }
  __syncthreads();

  float* w_lds = reinterpret_cast<float*>(idx_s);  // idx no longer needed
  if (t < 64) {
    const int m = t;
    float mx = -1e30f;
    for (int j2 = 0; j2 < NC; ++j2) mx = fmaxf(mx, C_lds[m * 113 + j2]);
    float sum = 0.0f;
    for (int j2 = 0; j2 < NC; ++j2) sum += expf(C_lds[m * 113 + j2] - mx);
    const float p = expf(C_lds[m * 113 + c] - mx) / sum;
    const float KL = log2f((1.0f + EPSF) / (p + EPSF));
    w_lds[m] = expf(KL * (*pgamma));
  }
  __syncthreads();
  {
    const int j = t;
    float kwv = 0.0f;
#pragma unroll 8
    for (int m = 0; m < 64; ++m) kwv += w_lds[m] * bf2f(A_lds[m * 264 + j]);
    kw_buf[c * 256 + j] = kwv;
  }
}

// ---------------------------------------------------------------------------
// Kernel 4: out[b][c] = alpha*exp(beta*cache-beta) + exp(ls)*dot(fn_b,text_c)
// cache = (1/64) * sum_j fn[b][idx[c][j]] * kw[c][j].  grid 100 x 256.
// Barrier-free: wave w handles b = w, w+4, ... — shuffle reductions only.
// ---------------------------------------------------------------------------
__global__ __launch_bounds__(256) void final_kernel(
    const float* __restrict__ fn, const float* __restrict__ text,
    const int* __restrict__ indices, const float* __restrict__ kw_buf,
    const float* __restrict__ pls, const float* __restrict__ palpha,
    const float* __restrict__ pbeta, float* __restrict__ out) {
  const int c = blockIdx.x;
  const int wv = threadIdx.x >> 6, lane = threadIdx.x & 63;

  int idx4[4];
  float kw4[4];
#pragma unroll
  for (int i = 0; i < 4; ++i) {
    idx4[i] = indices[c * 256 + i * 64 + lane];
    kw4[i] = kw_buf[c * 256 + i * 64 + lane];
  }
  float tc[8];
#pragma unroll
  for (int i = 0; i < 8; ++i) tc[i] = text[c * 512 + i * 64 + lane];
  const float ls = expf(*pls);
  const float alpha = *palpha, beta = *pbeta;

  for (int b = wv; b < 64; b += 4) {
    const float* fr = fn + b * DD;
    float cp = 0.0f, lp = 0.0f;
#pragma unroll
    for (int i = 0; i < 4; ++i) cp += fr[idx4[i]] * kw4[i];
#pragma unroll
    for (int i = 0; i < 8; ++i) lp += fr[i * 64 + lane] * tc[i];
#pragma unroll
    for (int o = 32; o; o >>= 1) {
      cp += __shfl_xor(cp, o);
      lp += __shfl_xor(lp, o);
    }
    if (lane == 0)
      out[b * NC + c] =
          alpha * expf(beta * (cp * (1.0f / 64.0f)) - beta) + ls * lp;
  }
}

// ---------------------------------------------------------------------------
extern "C" void kernel_launch(void* const* d_in, const int* in_sizes, int n_in,
                              void* d_out, int out_size, void* d_ws,
                              size_t ws_size, hipStream_t stream) {
  const float* image = (const float*)d_in[0];
  const float* W = (const float*)d_in[1];
  const float* text = (const float*)d_in[2];
  const float* keys = (const float*)d_in[3];
  const float* pls = (const float*)d_in[4];
  const int* idx = (const int*)d_in[5];
  const float* palpha = (const float*)d_in[6];
  const float* pbeta = (const float*)d_in[7];
  const float* pgamma = (const float*)d_in[8];
  float* out = (float*)d_out;

  char* ws = (char*)d_ws;
  float* f_part = (float*)(ws);                  // 256*64*512*4 = 33554432 B
  float* f_buf = (float*)(ws + 33554432);        // 64*512*4     = 131072 B
  float* fn = (float*)(ws + 33554432 + 131072);  // 64*512*4     = 131072 B
  float* kw = (float*)(ws + 33554432 + 262144);  // 100*256*4    = 102400 B

  gemm_f<<<256, 256, 0, stream>>>(image, W, f_part);
  reduce_f<<<256, 128, 0, stream>>>(f_part, f_buf);
  norm_f<<<64, 64, 0, stream>>>(f_buf, fn);
  wk_kernel<<<NC, 256, 0, stream>>>(text, keys, idx, pgamma, kw);
  final_kernel<<<NC, 256, 0, stream>>>(fn, text, idx, kw, pls, palpha, pbeta,
                                       out);
}